// Round 5
// baseline (1144.283 us; speedup 1.0000x reference)
//
#include <hip/hip_runtime.h>
#include <hip/hip_bf16.h>
#include <math.h>

#define NNODES 65536
#define NEDGES 1048576
#define NGRAPHS 64

typedef __attribute__((ext_vector_type(8))) short short8;
typedef __attribute__((ext_vector_type(4))) float f32x4;

// ---- order-preserving float<->uint encoding for atomicMax-based max ----
__device__ __forceinline__ unsigned encf(float f) {
    unsigned u = __float_as_uint(f);
    return (u & 0x80000000u) ? ~u : (u | 0x80000000u);
}
__device__ __forceinline__ float decf(unsigned u) {
    unsigned v = (u & 0x80000000u) ? (u & 0x7FFFFFFFu) : ~u;
    return __uint_as_float(v);
}
#define ENC_NEG_INF 0x007FFFFFu   // encf(-inf)

// RNE float -> bf16 bits (finite values only)
__device__ __forceinline__ unsigned bfbits(float f) {
    unsigned u = __float_as_uint(f);
    return (u + 0x7FFFu + ((u >> 16) & 1u)) >> 16;
}
__device__ __forceinline__ unsigned pk2(float a, float b) {
    return bfbits(a) | (bfbits(b) << 16);
}
__device__ __forceinline__ float bflo(unsigned p) { return __uint_as_float(p << 16); }
__device__ __forceinline__ float bfhi(unsigned p) { return __uint_as_float(p & 0xFFFF0000u); }

// CK-style barrier: drains LDS ops only; global loads-to-VGPR stay in flight
// (HIP __syncthreads would emit s_waitcnt vmcnt(0) and kill the V prefetch).
__device__ __forceinline__ void bar_sync() {
    __asm__ __volatile__("s_waitcnt lgkmcnt(0)\n\ts_barrier" ::: "memory");
}

__device__ __forceinline__ void storeY(float* p, float v) { *p = v; }
__device__ __forceinline__ void storeY(unsigned short* p, float v) { *p = (unsigned short)bfbits(v); }

// ============================ CSR build ============================
__global__ void k_init(int* deg, int* cursor, unsigned* poolEnc) {
    int i = blockIdx.x * 256 + threadIdx.x;
    if (i < NNODES) { deg[i] = 0; cursor[i] = 0; }
    if (i < NGRAPHS * 256) poolEnc[i] = ENC_NEG_INF;
}

__global__ void k_count(const int* __restrict__ ei, int* deg) {
    int e = blockIdx.x * 256 + threadIdx.x;
    atomicAdd(&deg[ei[NEDGES + e]], 1);
}

__global__ void k_scan1(const int* __restrict__ deg, int* rowptr, int* bsum) {
    __shared__ int s[256];
    int t = threadIdx.x, b = blockIdx.x;
    int v = deg[b * 256 + t];
    s[t] = v;
    __syncthreads();
    for (int off = 1; off < 256; off <<= 1) {
        int x = (t >= off) ? s[t - off] : 0;
        __syncthreads();
        if (t >= off) s[t] += x;
        __syncthreads();
    }
    rowptr[b * 256 + t] = s[t] - v;       // local exclusive
    if (t == 255) bsum[b] = s[255];
}

__global__ void k_scan2(const int* __restrict__ bsum, int* boff) {
    __shared__ int s[256];
    int t = threadIdx.x;
    int v = bsum[t];
    s[t] = v;
    __syncthreads();
    for (int off = 1; off < 256; off <<= 1) {
        int x = (t >= off) ? s[t - off] : 0;
        __syncthreads();
        if (t >= off) s[t] += x;
        __syncthreads();
    }
    boff[t] = s[t] - v;                   // exclusive block offsets
}

__global__ void k_scan3(int* rowptr, const int* __restrict__ boff) {
    int i = blockIdx.x * 256 + threadIdx.x;
    rowptr[i] += boff[blockIdx.x];
    if (i == 0) rowptr[NNODES] = NEDGES;
}

__global__ void k_scatter(const int* __restrict__ ei, const int* __restrict__ rowptr,
                          int* cursor, int* csr_src, int* csr_dst) {
    int e = blockIdx.x * 256 + threadIdx.x;
    int s = ei[e], d = ei[NEDGES + e];
    int pos = rowptr[d] + atomicAdd(&cursor[d], 1);
    csr_src[pos] = s;
    csr_dst[pos] = d;
}

// ============== layer-1 U/V precompute (scalar, FIN=3 is trivial) ==============
template <int FIN, int H>
__global__ __launch_bounds__(256) void k_uv(const float* __restrict__ X,
                                            const float* __restrict__ W1,
                                            const float* __restrict__ B1,
                                            float* __restrict__ U,
                                            unsigned short* __restrict__ Vb) {
    constexpr int NPT = (16 * H) / 256;
    __shared__ float xs[16][FIN];
    int tid = threadIdx.x;
    int n0 = blockIdx.x * 16;
    for (int idx = tid; idx < 16 * FIN; idx += 256)
        xs[idx / FIN][idx % FIN] = X[(size_t)(n0 + idx / FIN) * FIN + (idx % FIN)];
    __syncthreads();
    int h = tid & (H - 1);
    int nb = (tid / H) * NPT;
    float u[NPT], v[NPT];
    float bb = B1[h];
#pragma unroll
    for (int n = 0; n < NPT; n++) { u[n] = bb; v[n] = 0.f; }
    for (int f = 0; f < FIN; f++) {
        float wt = W1[f * H + h];
        float wb = W1[(FIN + f) * H + h];
        float wd = wt - wb;
#pragma unroll
        for (int n = 0; n < NPT; n++) {
            float xv = xs[nb + n][f];
            u[n] += xv * wd;
            v[n] += xv * wb;
        }
    }
#pragma unroll
    for (int n = 0; n < NPT; n++) {
        U[(size_t)(n0 + nb + n) * H + h] = u[n];
        Vb[(size_t)(n0 + nb + n) * H + h] = (unsigned short)bfbits(v[n]);
    }
}

// ============== layers-2/3 U/V precompute via MFMA ==============
// [U | V] = X @ [Wd | Wb], Wd = W1_top - W1_bot, Wb = W1_bot. X is bf16.
template <int K, int H, int CWAVES>
__global__ __launch_bounds__(CWAVES * 64, 4)
void k_uvm(const unsigned short* __restrict__ Xb,
           const float* __restrict__ W1,
           const float* __restrict__ B1,
           float* __restrict__ U,
           unsigned short* __restrict__ Vb) {
    constexpr int BLOCK = CWAVES * 64;
    constexpr int KP = K + 8;
    constexpr int CPW = (2 * H) / CWAVES;
    constexpr int NT = CPW / 16;
    constexpr int KS = K / 32;
    static_assert(BLOCK == 32 * (K / 8), "X-stage mapping");

    __shared__ unsigned short xs[32 * KP];

    int tid = threadIdx.x;
    int n0 = blockIdx.x * 32;
    int ln = tid & 15;
    int qd = (tid >> 4) & 3;
    int cw = tid >> 6;

    // stage X tile (32 x K bf16), padded stride
    {
        int r = tid / (K / 8);
        int ck = (tid % (K / 8)) * 8;
        uint4 w = *(const uint4*)&Xb[(size_t)(n0 + r) * K + ck];
        *(uint4*)&xs[r * KP + ck] = w;
    }

    // B fragments: cols [0,H) = Wd, [H,2H) = Wb
    short8 Bf[NT][KS];
#pragma unroll
    for (int nt = 0; nt < NT; nt++) {
        int col = cw * CPW + nt * 16 + ln;
#pragma unroll
        for (int ks = 0; ks < KS; ks++) {
            int kb = ks * 32 + qd * 8;
            short8 b;
#pragma unroll
            for (int j = 0; j < 8; j++) {
                int k = kb + j;
                float v;
                if (col < H) v = W1[(size_t)k * H + col] - W1[(size_t)(K + k) * H + col];
                else         v = W1[(size_t)(K + k) * H + (col - H)];
                b[j] = (short)bfbits(v);
            }
            Bf[nt][ks] = b;
        }
    }
    __syncthreads();

    f32x4 acc[2][NT];
#pragma unroll
    for (int mt = 0; mt < 2; mt++)
#pragma unroll
        for (int nt = 0; nt < NT; nt++)
            acc[mt][nt] = (f32x4){0.f, 0.f, 0.f, 0.f};

#pragma unroll
    for (int ks = 0; ks < KS; ks++) {
        int ko = ks * 32 + qd * 8;
        short8 a0 = *(const short8*)&xs[ln * KP + ko];
        short8 a1 = *(const short8*)&xs[(16 + ln) * KP + ko];
#pragma unroll
        for (int nt = 0; nt < NT; nt++) {
            acc[0][nt] = __builtin_amdgcn_mfma_f32_16x16x32_bf16(a0, Bf[nt][ks], acc[0][nt], 0, 0, 0);
            acc[1][nt] = __builtin_amdgcn_mfma_f32_16x16x32_bf16(a1, Bf[nt][ks], acc[1][nt], 0, 0, 0);
        }
    }

#pragma unroll
    for (int mt = 0; mt < 2; mt++) {
#pragma unroll
        for (int nt = 0; nt < NT; nt++) {
            int col = cw * CPW + nt * 16 + ln;
#pragma unroll
            for (int j = 0; j < 4; j++) {
                int node = n0 + mt * 16 + qd * 4 + j;
                float v = acc[mt][nt][j];
                if (col < H) U[(size_t)node * H + col] = v + B1[col];
                else         Vb[(size_t)node * H + (col - H)] = (unsigned short)bfbits(v);
            }
        }
    }
}

// ================= fused edge-GEMM (MFMA bf16) + segment-max =================
// Block owns 16 dst nodes + all their in-edges (CSR) -> no global atomics.
// V gather is software-pipelined through REGISTERS one tile ahead (indices two
// tiles ahead); bar_sync drains LDS only, so the global V loads stay in flight
// across both per-tile barriers and resolve during the next tile's rotation.
template <int H, int F, int RWAVES, int CWAVES, int MINW, typename YT>
__global__ __launch_bounds__(RWAVES * CWAVES * 64, MINW)
void k_agg(const float* __restrict__ U,
           const unsigned short* __restrict__ Vb,
           const float* __restrict__ W2,
           const float* __restrict__ B2,
           const int* __restrict__ rowptr,
           const int* __restrict__ csr_src,
           const int* __restrict__ csr_dst,
           YT* __restrict__ Y) {
    constexpr int BLOCK = RWAVES * CWAVES * 64;
    constexpr int TR = 32 * RWAVES;         // edge rows per tile
    constexpr int HP = H + 8;               // padded hs row (bf16 units)
    constexpr int CPW = F / CWAVES;         // cols per wave
    constexpr int NT = CPW / 16;
    constexpr int KS = H / 32;
    constexpr int ACCSTR = F + 1;
    constexpr int LPR = H / 8;              // threads per hs row (8 elems each)
    constexpr int RPP = BLOCK / LPR;        // rows per construction pass
    static_assert(TR == 2 * RPP, "construction must be exactly 2 passes");

    __shared__ unsigned short hs[TR * HP];   // hidden tile, bf16
    __shared__ unsigned accs[16 * ACCSTR];   // per-slot running max (encoded)
    __shared__ signed char slotS[2][TR];

    int tid = threadIdx.x;
    int n0 = blockIdx.x * 16;

    int ln = tid & 15;
    int qd = (tid >> 4) & 3;
    int wv = tid >> 6;
    int rw = wv / CWAVES;
    int cw = wv % CWAVES;

    // ---- W2 fragments in registers, once ----
    short8 Bf[NT][KS];
#pragma unroll
    for (int nt = 0; nt < NT; nt++) {
        int col = cw * CPW + nt * 16 + ln;
#pragma unroll
        for (int ks = 0; ks < KS; ks++) {
            int kb = ks * 32 + qd * 8;
            short8 b;
#pragma unroll
            for (int j = 0; j < 8; j++)
                b[j] = (short)bfbits(W2[(size_t)(kb + j) * F + col]);
            Bf[nt][ks] = b;
        }
    }

    for (int idx = tid; idx < 16 * ACCSTR; idx += BLOCK) accs[idx] = ENC_NEG_INF;

    int e0 = rowptr[n0], e1 = rowptr[n0 + 16];

    // construction mapping: 2 rows per thread (rid and rid+RPP), 8 elems each
    int rid = tid / LPR;
    int kk = (tid % LPR) * 8;

    // pipeline registers (per construction row)
    uint4 vA0, vA1;                // V data, current tile
    uint4 vB0, vB1;                // V data, next tile (in flight)
    int dst1_0, dst1_1;            // dst idx for next tile (resolved)
    int src2_0, src2_1;            // src idx, tile+2 (in flight)
    int dst2_0, dst2_1;            // dst idx, tile+2 (in flight)
    int dst0_0 = 0, dst0_1 = 0;    // dst idx for current tile

    if (e0 < e1) {
        // tile-0 indices (resolved immediately)
        int p0 = e0 + rid, p1 = e0 + rid + RPP;
        int sT0 = csr_src[p0], sT1 = csr_src[p1];
        dst1_0 = csr_dst[p0];  dst1_1 = csr_dst[p1];
        // tile-1 indices in flight
        src2_0 = csr_src[p0 + TR]; src2_1 = csr_src[p1 + TR];
        dst2_0 = csr_dst[p0 + TR]; dst2_1 = csr_dst[p1 + TR];
        // V(tile 0) into vB
        int sE0 = (p0 < e1) ? sT0 : 0;
        int sE1 = (p1 < e1) ? sT1 : 0;
        vB0 = *(const uint4*)&Vb[(size_t)sE0 * H + kk];
        vB1 = *(const uint4*)&Vb[(size_t)sE1 * H + kk];
        // slotS[0] for tile 0
        if (tid < TR) {
            int p = e0 + tid;
            slotS[0][tid] = (p < e1) ? (signed char)(csr_dst[p] - n0) : -1;
        }
    }
    bar_sync();   // accs + slotS visible

    int cur = 0;
    for (int base = e0; base < e1; base += TR, cur ^= 1) {
        // ---- rotate pipeline (waits land here, one full iter after issue) ----
        vA0 = vB0; vA1 = vB1;
        dst0_0 = dst1_0; dst0_1 = dst1_1;
        int src1_0 = src2_0, src1_1 = src2_1;
        dst1_0 = dst2_0; dst1_1 = dst2_1;

        // ---- issue tile+2 indices ----
        {
            int p0 = base + 2 * TR + rid, p1 = base + 2 * TR + rid + RPP;
            src2_0 = csr_src[p0]; src2_1 = csr_src[p1];   // OOB-safe: ws memory
            dst2_0 = csr_dst[p0]; dst2_1 = csr_dst[p1];
        }
        // ---- issue V loads for tile+1 ----
        {
            int p0 = base + TR + rid, p1 = base + TR + rid + RPP;
            int sE0 = (p0 < e1) ? src1_0 : 0;
            int sE1 = (p1 < e1) ? src1_1 : 0;
            vB0 = *(const uint4*)&Vb[(size_t)sE0 * H + kk];
            vB1 = *(const uint4*)&Vb[(size_t)sE1 * H + kk];
        }

        // ---- construct hidden tile: hs[r][k] = bf16(relu(U[dst,k] + V[src,k])) ----
        {
            int q0 = base + rid, q1 = base + rid + RPP;
            bool ok0 = q0 < e1, ok1 = q1 < e1;
            int dE0 = ok0 ? dst0_0 : 0;
            int dE1 = ok1 ? dst0_1 : 0;
            const float4 ua0 = *(const float4*)&U[(size_t)dE0 * H + kk];
            const float4 ub0 = *(const float4*)&U[(size_t)dE0 * H + kk + 4];
            const float4 ua1 = *(const float4*)&U[(size_t)dE1 * H + kk];
            const float4 ub1 = *(const float4*)&U[(size_t)dE1 * H + kk + 4];
            uint4 w0, w1;
            w0.x = pk2(fmaxf(ua0.x + bflo(vA0.x), 0.f), fmaxf(ua0.y + bfhi(vA0.x), 0.f));
            w0.y = pk2(fmaxf(ua0.z + bflo(vA0.y), 0.f), fmaxf(ua0.w + bfhi(vA0.y), 0.f));
            w0.z = pk2(fmaxf(ub0.x + bflo(vA0.z), 0.f), fmaxf(ub0.y + bfhi(vA0.z), 0.f));
            w0.w = pk2(fmaxf(ub0.z + bflo(vA0.w), 0.f), fmaxf(ub0.w + bfhi(vA0.w), 0.f));
            w1.x = pk2(fmaxf(ua1.x + bflo(vA1.x), 0.f), fmaxf(ua1.y + bfhi(vA1.x), 0.f));
            w1.y = pk2(fmaxf(ua1.z + bflo(vA1.y), 0.f), fmaxf(ua1.w + bfhi(vA1.y), 0.f));
            w1.z = pk2(fmaxf(ub1.x + bflo(vA1.z), 0.f), fmaxf(ub1.y + bfhi(vA1.z), 0.f));
            w1.w = pk2(fmaxf(ub1.z + bflo(vA1.w), 0.f), fmaxf(ub1.w + bfhi(vA1.w), 0.f));
            if (!ok0) w0 = (uint4){0u, 0u, 0u, 0u};
            if (!ok1) w1 = (uint4){0u, 0u, 0u, 0u};
            *(uint4*)&hs[rid * HP + kk] = w0;
            *(uint4*)&hs[(rid + RPP) * HP + kk] = w1;
        }
        bar_sync();   // hs ready (lgkm drain only; V loads stay outstanding)

        // ---- slot maintenance for next tile (overlaps MFMA) ----
        if (tid < TR) {
            int p = base + TR + tid;
            int d = csr_dst[p];
            slotS[cur ^ 1][tid] = (p < e1) ? (signed char)(d - n0) : -1;
        }

        // ---- MFMA ----
        f32x4 acc[2][NT];
#pragma unroll
        for (int mt = 0; mt < 2; mt++)
#pragma unroll
            for (int nt = 0; nt < NT; nt++)
                acc[mt][nt] = (f32x4){0.f, 0.f, 0.f, 0.f};

#pragma unroll
        for (int ks = 0; ks < KS; ks++) {
            int ko = ks * 32 + qd * 8;
            short8 a0 = *(const short8*)&hs[(rw * 32 + ln) * HP + ko];
            short8 a1 = *(const short8*)&hs[(rw * 32 + 16 + ln) * HP + ko];
#pragma unroll
            for (int nt = 0; nt < NT; nt++) {
                acc[0][nt] = __builtin_amdgcn_mfma_f32_16x16x32_bf16(a0, Bf[nt][ks], acc[0][nt], 0, 0, 0);
                acc[1][nt] = __builtin_amdgcn_mfma_f32_16x16x32_bf16(a1, Bf[nt][ks], acc[1][nt], 0, 0, 0);
            }
        }

        // ---- merge slot-runs in regs, then LDS atomicMax ----
#pragma unroll
        for (int mt = 0; mt < 2; mt++) {
            int rbase = rw * 32 + mt * 16 + qd * 4;
            char4 ss = *(const char4*)&slotS[cur][rbase];
#pragma unroll
            for (int nt = 0; nt < NT; nt++) {
                int colw = cw * CPW + nt * 16 + ln;
                float c0 = acc[mt][nt][0], c1 = acc[mt][nt][1];
                float c2 = acc[mt][nt][2], c3 = acc[mt][nt][3];
                float m3 = c3;
                float m2 = (ss.z == ss.w) ? fmaxf(c2, m3) : c2;
                float m1 = (ss.y == ss.z) ? fmaxf(c1, m2) : c1;
                float m0 = (ss.x == ss.y) ? fmaxf(c0, m1) : c0;
                if (ss.x >= 0)                 atomicMax(&accs[(int)ss.x * ACCSTR + colw], encf(m0));
                if (ss.y >= 0 && ss.y != ss.x) atomicMax(&accs[(int)ss.y * ACCSTR + colw], encf(m1));
                if (ss.z >= 0 && ss.z != ss.y) atomicMax(&accs[(int)ss.z * ACCSTR + colw], encf(m2));
                if (ss.w >= 0 && ss.w != ss.z) atomicMax(&accs[(int)ss.w * ACCSTR + colw], encf(m3));
            }
        }
        bar_sync();   // atomics + slot writes drained; hs consumed
    }

    bar_sync();
    for (int idx = tid; idx < 16 * F; idx += BLOCK) {
        int sl = idx / F, cc = idx % F;
        float m = decf(accs[sl * ACCSTR + cc]);
        float o = isfinite(m) ? (m + B2[cc]) : 0.f;   // empty segment -> 0
        storeY(&Y[(size_t)(n0 + sl) * F + cc], o);
    }
}

// ============================ global max-pool + FC ============================
__global__ void k_pool(const float* __restrict__ X3, const int* __restrict__ batch,
                       unsigned* poolEnc) {
    int gph = blockIdx.x;
    int seg = blockIdx.y;
    int c = threadIdx.x;
    int lo = 0, hi = NNODES;
    while (lo < hi) { int mid = (lo + hi) >> 1; if (batch[mid] < gph) lo = mid + 1; else hi = mid; }
    int start = lo;
    hi = NNODES;
    while (lo < hi) { int mid = (lo + hi) >> 1; if (batch[mid] < gph + 1) lo = mid + 1; else hi = mid; }
    int end = lo;
    int chunk = (end - start + 7) >> 3;
    int s = start + seg * chunk;
    int e = min(end, s + chunk);
    float m = -INFINITY;
    for (int n = s; n < e; n++) m = fmaxf(m, X3[(size_t)n * 256 + c]);
    atomicMax(&poolEnc[gph * 256 + c], encf(m));
}

__global__ __launch_bounds__(128) void k_fc(const unsigned* __restrict__ poolEnc,
                                            const float* __restrict__ Wfc,
                                            const float* __restrict__ Bfc,
                                            float* __restrict__ out) {
    __shared__ float p[256];
    int gph = blockIdx.x, c = threadIdx.x;
    for (int k = c; k < 256; k += 128) {
        float m = decf(poolEnc[gph * 256 + k]);
        p[k] = isfinite(m) ? m : 0.f;
    }
    __syncthreads();
    float s = Bfc[c];
    for (int k = 0; k < 256; k++) s += p[k] * Wfc[k * 128 + c];
    out[gph * 128 + c] = s;
}

// ============================ launch ============================
extern "C" void kernel_launch(void* const* d_in, const int* in_sizes, int n_in,
                              void* d_out, int out_size, void* d_ws, size_t ws_size,
                              hipStream_t stream) {
    const float* x     = (const float*)d_in[0];
    const int*   ei    = (const int*)d_in[1];
    const int*   batch = (const int*)d_in[2];
    const float* w1_1 = (const float*)d_in[3];
    const float* b1_1 = (const float*)d_in[4];
    const float* w2_1 = (const float*)d_in[5];
    const float* b2_1 = (const float*)d_in[6];
    const float* w1_2 = (const float*)d_in[7];
    const float* b1_2 = (const float*)d_in[8];
    const float* w2_2 = (const float*)d_in[9];
    const float* b2_2 = (const float*)d_in[10];
    const float* w1_3 = (const float*)d_in[11];
    const float* b1_3 = (const float*)d_in[12];
    const float* w2_3 = (const float*)d_in[13];
    const float* b2_3 = (const float*)d_in[14];
    const float* wfc  = (const float*)d_in[15];
    const float* bfc  = (const float*)d_in[16];
    float* out = (float*)d_out;

    char* ws = (char*)d_ws;
    size_t off = 0;
    auto alloc = [&](size_t bytes) {
        void* p = ws + off;
        off = (off + bytes + 255) & ~(size_t)255;
        return p;
    };
    int* deg      = (int*)alloc((size_t)NNODES * 4);
    int* cursor   = (int*)alloc((size_t)NNODES * 4);
    int* rowptr   = (int*)alloc((size_t)(NNODES + 1) * 4);
    int* bsum     = (int*)alloc(256 * 4);
    int* boff     = (int*)alloc(256 * 4);
    int* csr_src  = (int*)alloc((size_t)NEDGES * 4);
    int* csr_dst  = (int*)alloc((size_t)NEDGES * 4);
    float* U      = (float*)alloc((size_t)NNODES * 256 * 4);
    unsigned short* V = (unsigned short*)alloc((size_t)NNODES * 256 * 2);
    unsigned short* x1b = (unsigned short*)alloc((size_t)NNODES * 64 * 2);
    unsigned short* x2b = (unsigned short*)alloc((size_t)NNODES * 128 * 2);
    float* x3     = (float*)alloc((size_t)NNODES * 256 * 4);
    unsigned* poolEnc = (unsigned*)alloc((size_t)NGRAPHS * 256 * 4);
    (void)ws_size; (void)in_sizes; (void)n_in; (void)out_size;

    // CSR by dst (shared across the 3 layers)
    k_init<<<256, 256, 0, stream>>>(deg, cursor, poolEnc);
    k_count<<<NEDGES / 256, 256, 0, stream>>>(ei, deg);
    k_scan1<<<256, 256, 0, stream>>>(deg, rowptr, bsum);
    k_scan2<<<1, 256, 0, stream>>>(bsum, boff);
    k_scan3<<<256, 256, 0, stream>>>(rowptr, boff);
    k_scatter<<<NEDGES / 256, 256, 0, stream>>>(ei, rowptr, cursor, csr_src, csr_dst);

    // layer 1: FIN=3, H=64, F=64  (scalar uv; agg 2x2 waves, TR=64) -> x1 bf16
    k_uv<3, 64><<<NNODES / 16, 256, 0, stream>>>(x, w1_1, b1_1, U, V);
    k_agg<64, 64, 2, 2, 4, unsigned short><<<NNODES / 16, 256, 0, stream>>>(U, V, w2_1, b2_1, rowptr, csr_src, csr_dst, x1b);
    // layer 2: K=64, H=128, F=128 (MFMA uv; agg 1x4 waves, TR=32) -> x2 bf16
    k_uvm<64, 128, 4><<<NNODES / 32, 256, 0, stream>>>(x1b, w1_2, b1_2, U, V);
    k_agg<128, 128, 1, 4, 4, unsigned short><<<NNODES / 16, 256, 0, stream>>>(U, V, w2_2, b2_2, rowptr, csr_src, csr_dst, x2b);
    // layer 3: K=128, H=256, F=256 (MFMA uv; agg 1x8 waves, TR=32) -> x3 fp32
    k_uvm<128, 256, 8><<<NNODES / 32, 512, 0, stream>>>(x2b, w1_3, b1_3, U, V);
    k_agg<256, 256, 1, 8, 3, float><<<NNODES / 16, 512, 0, stream>>>(U, V, w2_3, b2_3, rowptr, csr_src, csr_dst, x3);

    // global max pool + FC
    k_pool<<<dim3(NGRAPHS, 8), 256, 0, stream>>>(x3, batch, poolEnc);
    k_fc<<<NGRAPHS, 128, 0, stream>>>(poolEnc, wfc, bfc, out);
}

// Round 7
// 1017.583 us; speedup vs baseline: 1.1245x; 1.1245x over previous
//
#include <hip/hip_runtime.h>
#include <hip/hip_fp16.h>
#include <math.h>

#define NNODES 65536
#define NEDGES 1048576
#define NGRAPHS 64

typedef __attribute__((ext_vector_type(8))) _Float16 half8;
typedef __attribute__((ext_vector_type(2))) _Float16 h2v;
typedef __attribute__((ext_vector_type(4))) float f32x4;

// ---- order-preserving float<->uint encoding for atomicMax-based max ----
__device__ __forceinline__ unsigned encf(float f) {
    unsigned u = __float_as_uint(f);
    return (u & 0x80000000u) ? ~u : (u | 0x80000000u);
}
__device__ __forceinline__ float decf(unsigned u) {
    unsigned v = (u & 0x80000000u) ? (u & 0x7FFFFFFFu) : ~u;
    return __uint_as_float(v);
}
#define ENC_NEG_INF 0x007FFFFFu   // encf(-inf)

// CK-style barrier: drains LDS ops only (no vmcnt(0) like __syncthreads).
__device__ __forceinline__ void bar_sync() {
    __asm__ __volatile__("s_waitcnt lgkmcnt(0)\n\ts_barrier" ::: "memory");
}

__device__ __forceinline__ unsigned short f2h(float v) {
    return __half_as_ushort(__float2half(v));
}
__device__ __forceinline__ void storeY(float* p, float v) { *p = v; }
__device__ __forceinline__ void storeY(unsigned short* p, float v) { *p = f2h(v); }

// relu(u+v) on 8 packed f16 (v_pk_add_f16 + v_pk_max_f16)
__device__ __forceinline__ uint4 hpack(uint4 u, uint4 v) {
    union P { uint4 q; h2v h[4]; };
    P U, V, W;
    U.q = u; V.q = v;
    h2v z = (h2v)(_Float16)0.0f;
#pragma unroll
    for (int j = 0; j < 4; j++) {
        h2v s = U.h[j] + V.h[j];
        W.h[j] = __builtin_elementwise_max(s, z);
    }
    return W.q;
}

// ============================ CSR build ============================
__global__ void k_init(int* deg, int* cursor, unsigned* poolEnc) {
    int i = blockIdx.x * 256 + threadIdx.x;
    if (i < NNODES) { deg[i] = 0; cursor[i] = 0; }
    if (i < NGRAPHS * 256) poolEnc[i] = ENC_NEG_INF;
}

__global__ void k_count(const int* __restrict__ ei, int* deg) {
    int e = blockIdx.x * 256 + threadIdx.x;
    atomicAdd(&deg[ei[NEDGES + e]], 1);
}

__global__ void k_scan1(const int* __restrict__ deg, int* rowptr, int* bsum) {
    __shared__ int s[256];
    int t = threadIdx.x, b = blockIdx.x;
    int v = deg[b * 256 + t];
    s[t] = v;
    __syncthreads();
    for (int off = 1; off < 256; off <<= 1) {
        int x = (t >= off) ? s[t - off] : 0;
        __syncthreads();
        if (t >= off) s[t] += x;
        __syncthreads();
    }
    rowptr[b * 256 + t] = s[t] - v;       // local exclusive
    if (t == 255) bsum[b] = s[255];
}

__global__ void k_scan2(const int* __restrict__ bsum, int* boff) {
    __shared__ int s[256];
    int t = threadIdx.x;
    int v = bsum[t];
    s[t] = v;
    __syncthreads();
    for (int off = 1; off < 256; off <<= 1) {
        int x = (t >= off) ? s[t - off] : 0;
        __syncthreads();
        if (t >= off) s[t] += x;
        __syncthreads();
    }
    boff[t] = s[t] - v;                   // exclusive block offsets
}

__global__ void k_scan3(int* rowptr, const int* __restrict__ boff) {
    int i = blockIdx.x * 256 + threadIdx.x;
    rowptr[i] += boff[blockIdx.x];
    if (i == 0) rowptr[NNODES] = NEDGES;
}

__global__ void k_scatter(const int* __restrict__ ei, const int* __restrict__ rowptr,
                          int* cursor, int* csr_src, int* csr_dst) {
    int e = blockIdx.x * 256 + threadIdx.x;
    int s = ei[e], d = ei[NEDGES + e];
    int pos = rowptr[d] + atomicAdd(&cursor[d], 1);
    csr_src[pos] = s;
    csr_dst[pos] = d;
}

// ============== layer-1 U/V precompute (scalar, FIN=3 is trivial) ==============
template <int FIN, int H>
__global__ __launch_bounds__(256) void k_uv(const float* __restrict__ X,
                                            const float* __restrict__ W1,
                                            const float* __restrict__ B1,
                                            unsigned short* __restrict__ Uh,
                                            unsigned short* __restrict__ Vh) {
    constexpr int NPT = (16 * H) / 256;
    __shared__ float xs[16][FIN];
    int tid = threadIdx.x;
    int n0 = blockIdx.x * 16;
    for (int idx = tid; idx < 16 * FIN; idx += 256)
        xs[idx / FIN][idx % FIN] = X[(size_t)(n0 + idx / FIN) * FIN + (idx % FIN)];
    __syncthreads();
    int h = tid & (H - 1);
    int nb = (tid / H) * NPT;
    float u[NPT], v[NPT];
    float bb = B1[h];
#pragma unroll
    for (int n = 0; n < NPT; n++) { u[n] = bb; v[n] = 0.f; }
    for (int f = 0; f < FIN; f++) {
        float wt = W1[f * H + h];
        float wb = W1[(FIN + f) * H + h];
        float wd = wt - wb;
#pragma unroll
        for (int n = 0; n < NPT; n++) {
            float xv = xs[nb + n][f];
            u[n] += xv * wd;
            v[n] += xv * wb;
        }
    }
#pragma unroll
    for (int n = 0; n < NPT; n++) {
        Uh[(size_t)(n0 + nb + n) * H + h] = f2h(u[n]);
        Vh[(size_t)(n0 + nb + n) * H + h] = f2h(v[n]);
    }
}

// ============== layers-2/3 U/V precompute via MFMA (f16) ==============
// [U | V] = X @ [Wd | Wb], Wd = W1_top - W1_bot, Wb = W1_bot. X is f16.
template <int K, int H, int CWAVES>
__global__ __launch_bounds__(CWAVES * 64, 4)
void k_uvm(const unsigned short* __restrict__ Xh,
           const float* __restrict__ W1,
           const float* __restrict__ B1,
           unsigned short* __restrict__ Uh,
           unsigned short* __restrict__ Vh) {
    constexpr int BLOCK = CWAVES * 64;
    constexpr int KP = K + 8;
    constexpr int CPW = (2 * H) / CWAVES;
    constexpr int NT = CPW / 16;
    constexpr int KS = K / 32;
    static_assert(BLOCK == 32 * (K / 8), "X-stage mapping");

    __shared__ unsigned short xs[32 * KP];

    int tid = threadIdx.x;
    int n0 = blockIdx.x * 32;
    int ln = tid & 15;
    int qd = (tid >> 4) & 3;
    int cw = tid >> 6;

    // stage X tile (32 x K f16), padded stride
    {
        int r = tid / (K / 8);
        int ck = (tid % (K / 8)) * 8;
        uint4 w = *(const uint4*)&Xh[(size_t)(n0 + r) * K + ck];
        *(uint4*)&xs[r * KP + ck] = w;
    }

    // B fragments: cols [0,H) = Wd, [H,2H) = Wb
    half8 Bf[NT][KS];
#pragma unroll
    for (int nt = 0; nt < NT; nt++) {
        int col = cw * CPW + nt * 16 + ln;
#pragma unroll
        for (int ks = 0; ks < KS; ks++) {
            int kb = ks * 32 + qd * 8;
            half8 b;
#pragma unroll
            for (int j = 0; j < 8; j++) {
                int k = kb + j;
                float v;
                if (col < H) v = W1[(size_t)k * H + col] - W1[(size_t)(K + k) * H + col];
                else         v = W1[(size_t)(K + k) * H + (col - H)];
                b[j] = (_Float16)v;
            }
            Bf[nt][ks] = b;
        }
    }
    __syncthreads();

    f32x4 acc[2][NT];
#pragma unroll
    for (int mt = 0; mt < 2; mt++)
#pragma unroll
        for (int nt = 0; nt < NT; nt++)
            acc[mt][nt] = (f32x4){0.f, 0.f, 0.f, 0.f};

#pragma unroll
    for (int ks = 0; ks < KS; ks++) {
        int ko = ks * 32 + qd * 8;
        half8 a0 = *(const half8*)&xs[ln * KP + ko];
        half8 a1 = *(const half8*)&xs[(16 + ln) * KP + ko];
#pragma unroll
        for (int nt = 0; nt < NT; nt++) {
            acc[0][nt] = __builtin_amdgcn_mfma_f32_16x16x32_f16(a0, Bf[nt][ks], acc[0][nt], 0, 0, 0);
            acc[1][nt] = __builtin_amdgcn_mfma_f32_16x16x32_f16(a1, Bf[nt][ks], acc[1][nt], 0, 0, 0);
        }
    }

#pragma unroll
    for (int mt = 0; mt < 2; mt++) {
#pragma unroll
        for (int nt = 0; nt < NT; nt++) {
            int col = cw * CPW + nt * 16 + ln;
#pragma unroll
            for (int j = 0; j < 4; j++) {
                int node = n0 + mt * 16 + qd * 4 + j;
                float v = acc[mt][nt][j];
                if (col < H) Uh[(size_t)node * H + col] = f2h(v + B1[col]);
                else         Vh[(size_t)node * H + (col - H)] = f2h(v);
            }
        }
    }
}

// ========== fused edge-GEMM (MFMA f16) + segment-max, DUAL-STREAM ==========
// Block owns 32 dst nodes = two independent 16-node streams (contiguous CSR).
// Phases alternate [merge S1 | construct S0] bar [merge S0 | construct S1] bar,
// so every inter-barrier phase mixes latency-heavy gathers with MFMA compute.
template <int H, int F, int RWAVES, int CWAVES, int MINW, typename YT>
__global__ __launch_bounds__(RWAVES * CWAVES * 64, MINW)
void k_agg(const unsigned short* __restrict__ Uh,
           const unsigned short* __restrict__ Vh,
           const float* __restrict__ W2,
           const float* __restrict__ B2,
           const int* __restrict__ rowptr,
           const int* __restrict__ csr_src,
           const int* __restrict__ csr_dst,
           YT* __restrict__ Y) {
    constexpr int BLOCK = RWAVES * CWAVES * 64;
    constexpr int TR = 32 * RWAVES;         // edge rows per tile
    constexpr int HP = H + 8;               // padded hs row (f16 units)
    constexpr int CPW = F / CWAVES;         // cols per wave
    constexpr int NT = CPW / 16;
    constexpr int KS = H / 32;
    constexpr int ACCSTR = F + 1;
    constexpr int LPR = H / 8;              // threads per hs row
    constexpr int RPP = BLOCK / LPR;        // rows per construction pass
    static_assert(TR == 2 * RPP, "construction must be exactly 2 passes");

    __shared__ unsigned short hs0[TR * HP], hs1[TR * HP];
    __shared__ unsigned accs[32 * ACCSTR];   // slots 0-15: stream A, 16-31: stream B
    __shared__ signed char slot0[TR], slot1[TR];

    int tid = threadIdx.x;
    int nA = blockIdx.x * 32;                // stream A: [nA, nA+16), B: [nA+16, nA+32)

    int ln = tid & 15;
    int qd = (tid >> 4) & 3;
    int wv = tid >> 6;
    int rw = wv / CWAVES;
    int cw = wv % CWAVES;

    // ---- W2 fragments in registers (f16), once ----
    half8 Bf[NT][KS];
#pragma unroll
    for (int nt = 0; nt < NT; nt++) {
        int col = cw * CPW + nt * 16 + ln;
#pragma unroll
        for (int ks = 0; ks < KS; ks++) {
            int kb = ks * 32 + qd * 8;
            half8 b;
#pragma unroll
            for (int j = 0; j < 8; j++)
                b[j] = (_Float16)W2[(size_t)(kb + j) * F + col];
            Bf[nt][ks] = b;
        }
    }

    for (int idx = tid; idx < 32 * ACCSTR; idx += BLOCK) accs[idx] = ENC_NEG_INF;

    int e0a = rowptr[nA], e1a = rowptr[nA + 16], e1b = rowptr[nA + 32];
    int e0b = e1a;

    int rid = tid / LPR;            // construction: rows rid and rid+RPP
    int kk = (tid % LPR) * 8;       // 8-elem chunk

    // construct: load phase (issues gathers; use deferred past MFMA)
    auto cons_load = [&](int base, int e1, int& o0, int& o1,
                         uint4& v0, uint4& v1, uint4& u0, uint4& u1) {
        int p0 = base + rid, p1 = base + rid + RPP;
        o0 = p0 < e1; o1 = p1 < e1;
        int s0 = csr_src[p0], s1 = csr_src[p1];   // OOB-safe (ws memory)
        int d0 = csr_dst[p0], d1 = csr_dst[p1];
        s0 = o0 ? s0 : 0; d0 = o0 ? d0 : 0;
        s1 = o1 ? s1 : 0; d1 = o1 ? d1 : 0;
        v0 = *(const uint4*)&Vh[(size_t)s0 * H + kk];
        v1 = *(const uint4*)&Vh[(size_t)s1 * H + kk];
        u0 = *(const uint4*)&Uh[(size_t)d0 * H + kk];
        u1 = *(const uint4*)&Uh[(size_t)d1 * H + kk];
    };
    auto cons_store = [&](unsigned short* hsX, int o0, int o1,
                          uint4 v0, uint4 v1, uint4 u0, uint4 u1) {
        uint4 w0 = hpack(u0, v0), w1 = hpack(u1, v1);
        if (!o0) w0 = (uint4){0u, 0u, 0u, 0u};
        if (!o1) w1 = (uint4){0u, 0u, 0u, 0u};
        *(uint4*)&hsX[rid * HP + kk] = w0;
        *(uint4*)&hsX[(rid + RPP) * HP + kk] = w1;
    };
    auto slot_write = [&](signed char* slotX, int base, int e1, int nbase) {
        if (tid < TR) {
            int p = base + tid;
            int d = csr_dst[p];
            slotX[tid] = (p < e1) ? (signed char)(d - nbase) : -1;
        }
    };
    auto mfma_merge = [&](const unsigned short* hsX, const signed char* slotX, int slotbase) {
#pragma unroll
        for (int mt = 0; mt < 2; mt++) {
            f32x4 acc[NT];
#pragma unroll
            for (int nt = 0; nt < NT; nt++) acc[nt] = (f32x4){0.f, 0.f, 0.f, 0.f};
#pragma unroll
            for (int ks = 0; ks < KS; ks++) {
                int ko = ks * 32 + qd * 8;
                half8 a = *(const half8*)&hsX[(rw * 32 + mt * 16 + ln) * HP + ko];
#pragma unroll
                for (int nt = 0; nt < NT; nt++)
                    acc[nt] = __builtin_amdgcn_mfma_f32_16x16x32_f16(a, Bf[nt][ks], acc[nt], 0, 0, 0);
            }
            int rbase = rw * 32 + mt * 16 + qd * 4;
            char4 ss = *(const char4*)&slotX[rbase];
#pragma unroll
            for (int nt = 0; nt < NT; nt++) {
                int colw = cw * CPW + nt * 16 + ln;
                float c0 = acc[nt][0], c1 = acc[nt][1], c2 = acc[nt][2], c3 = acc[nt][3];
                float m3 = c3;
                float m2 = (ss.z == ss.w) ? fmaxf(c2, m3) : c2;
                float m1 = (ss.y == ss.z) ? fmaxf(c1, m2) : c1;
                float m0 = (ss.x == ss.y) ? fmaxf(c0, m1) : c0;
                if (ss.x >= 0)                 atomicMax(&accs[(slotbase + (int)ss.x) * ACCSTR + colw], encf(m0));
                if (ss.y >= 0 && ss.y != ss.x) atomicMax(&accs[(slotbase + (int)ss.y) * ACCSTR + colw], encf(m1));
                if (ss.z >= 0 && ss.z != ss.y) atomicMax(&accs[(slotbase + (int)ss.z) * ACCSTR + colw], encf(m2));
                if (ss.w >= 0 && ss.w != ss.z) atomicMax(&accs[(slotbase + (int)ss.w) * ACCSTR + colw], encf(m3));
            }
        }
    };

    int T0 = (e1a - e0a + TR - 1) / TR;
    int T1 = (e1b - e0b + TR - 1) / TR;
    int imax = (T0 > T1 + 1) ? T0 : (T1 + 1);

    for (int i = 0; i < imax; i++) {
        // ---- phase A: construct S0(i) overlapped with merge S1(i-1) ----
        uint4 v0, v1, u0, u1; int o0, o1;
        bool cA = (i < T0);
        if (cA) {
            cons_load(e0a + i * TR, e1a, o0, o1, v0, v1, u0, u1);
            slot_write(slot0, e0a + i * TR, e1a, nA);
        }
        if (i >= 1 && i - 1 < T1) mfma_merge(hs1, slot1, 16);
        if (cA) cons_store(hs0, o0, o1, v0, v1, u0, u1);
        bar_sync();

        // ---- phase B: construct S1(i) overlapped with merge S0(i) ----
        bool cB = (i < T1);
        if (cB) {
            cons_load(e0b + i * TR, e1b, o0, o1, v0, v1, u0, u1);
            slot_write(slot1, e0b + i * TR, e1b, nA + 16);
        }
        if (cA) mfma_merge(hs0, slot0, 0);
        if (cB) cons_store(hs1, o0, o1, v0, v1, u0, u1);
        bar_sync();
    }

    for (int idx = tid; idx < 32 * F; idx += BLOCK) {
        int sl = idx / F, cc = idx % F;
        float m = decf(accs[sl * ACCSTR + cc]);
        float o = isfinite(m) ? (m + B2[cc]) : 0.f;   // empty segment -> 0
        storeY(&Y[(size_t)(nA + sl) * F + cc], o);
    }
}

// ============================ global max-pool + FC ============================
__global__ void k_pool(const float* __restrict__ X3, const int* __restrict__ batch,
                       unsigned* poolEnc) {
    int gph = blockIdx.x;
    int seg = blockIdx.y;
    int c = threadIdx.x;
    int lo = 0, hi = NNODES;
    while (lo < hi) { int mid = (lo + hi) >> 1; if (batch[mid] < gph) lo = mid + 1; else hi = mid; }
    int start = lo;
    hi = NNODES;
    while (lo < hi) { int mid = (lo + hi) >> 1; if (batch[mid] < gph + 1) lo = mid + 1; else hi = mid; }
    int end = lo;
    int chunk = (end - start + 7) >> 3;
    int s = start + seg * chunk;
    int e = min(end, s + chunk);
    float m = -INFINITY;
    for (int n = s; n < e; n++) m = fmaxf(m, X3[(size_t)n * 256 + c]);
    atomicMax(&poolEnc[gph * 256 + c], encf(m));
}

__global__ __launch_bounds__(128) void k_fc(const unsigned* __restrict__ poolEnc,
                                            const float* __restrict__ Wfc,
                                            const float* __restrict__ Bfc,
                                            float* __restrict__ out) {
    __shared__ float p[256];
    int gph = blockIdx.x, c = threadIdx.x;
    for (int k = c; k < 256; k += 128) {
        float m = decf(poolEnc[gph * 256 + k]);
        p[k] = isfinite(m) ? m : 0.f;
    }
    __syncthreads();
    float s = Bfc[c];
    for (int k = 0; k < 256; k++) s += p[k] * Wfc[k * 128 + c];
    out[gph * 128 + c] = s;
}

// ============================ launch ============================
extern "C" void kernel_launch(void* const* d_in, const int* in_sizes, int n_in,
                              void* d_out, int out_size, void* d_ws, size_t ws_size,
                              hipStream_t stream) {
    const float* x     = (const float*)d_in[0];
    const int*   ei    = (const int*)d_in[1];
    const int*   batch = (const int*)d_in[2];
    const float* w1_1 = (const float*)d_in[3];
    const float* b1_1 = (const float*)d_in[4];
    const float* w2_1 = (const float*)d_in[5];
    const float* b2_1 = (const float*)d_in[6];
    const float* w1_2 = (const float*)d_in[7];
    const float* b1_2 = (const float*)d_in[8];
    const float* w2_2 = (const float*)d_in[9];
    const float* b2_2 = (const float*)d_in[10];
    const float* w1_3 = (const float*)d_in[11];
    const float* b1_3 = (const float*)d_in[12];
    const float* w2_3 = (const float*)d_in[13];
    const float* b2_3 = (const float*)d_in[14];
    const float* wfc  = (const float*)d_in[15];
    const float* bfc  = (const float*)d_in[16];
    float* out = (float*)d_out;

    char* ws = (char*)d_ws;
    size_t off = 0;
    auto alloc = [&](size_t bytes) {
        void* p = ws + off;
        off = (off + bytes + 255) & ~(size_t)255;
        return p;
    };
    int* deg      = (int*)alloc((size_t)NNODES * 4);
    int* cursor   = (int*)alloc((size_t)NNODES * 4);
    int* rowptr   = (int*)alloc((size_t)(NNODES + 1) * 4);
    int* bsum     = (int*)alloc(256 * 4);
    int* boff     = (int*)alloc(256 * 4);
    int* csr_src  = (int*)alloc((size_t)NEDGES * 4);
    int* csr_dst  = (int*)alloc((size_t)NEDGES * 4);
    unsigned short* U = (unsigned short*)alloc((size_t)NNODES * 256 * 2);
    unsigned short* V = (unsigned short*)alloc((size_t)NNODES * 256 * 2);
    unsigned short* x1h = (unsigned short*)alloc((size_t)NNODES * 64 * 2);
    unsigned short* x2h = (unsigned short*)alloc((size_t)NNODES * 128 * 2);
    float* x3     = (float*)alloc((size_t)NNODES * 256 * 4);
    unsigned* poolEnc = (unsigned*)alloc((size_t)NGRAPHS * 256 * 4);
    (void)ws_size; (void)in_sizes; (void)n_in; (void)out_size;

    // CSR by dst (shared across the 3 layers)
    k_init<<<256, 256, 0, stream>>>(deg, cursor, poolEnc);
    k_count<<<NEDGES / 256, 256, 0, stream>>>(ei, deg);
    k_scan1<<<256, 256, 0, stream>>>(deg, rowptr, bsum);
    k_scan2<<<1, 256, 0, stream>>>(bsum, boff);
    k_scan3<<<256, 256, 0, stream>>>(rowptr, boff);
    k_scatter<<<NEDGES / 256, 256, 0, stream>>>(ei, rowptr, cursor, csr_src, csr_dst);

    // layer 1: FIN=3, H=64, F=64  (scalar uv; dual-stream agg 2x2 waves, TR=64)
    k_uv<3, 64><<<NNODES / 16, 256, 0, stream>>>(x, w1_1, b1_1, U, V);
    k_agg<64, 64, 2, 2, 4, unsigned short><<<NNODES / 32, 256, 0, stream>>>(U, V, w2_1, b2_1, rowptr, csr_src, csr_dst, x1h);
    // layer 2: K=64, H=128, F=128 (f16 MFMA uv; dual-stream agg 1x4 waves, TR=32)
    k_uvm<64, 128, 4><<<NNODES / 32, 256, 0, stream>>>(x1h, w1_2, b1_2, U, V);
    k_agg<128, 128, 1, 4, 4, unsigned short><<<NNODES / 32, 256, 0, stream>>>(U, V, w2_2, b2_2, rowptr, csr_src, csr_dst, x2h);
    // layer 3: K=128, H=256, F=256 (f16 MFMA uv; dual-stream agg 1x8 waves, TR=32)
    k_uvm<128, 256, 8><<<NNODES / 32, 512, 0, stream>>>(x2h, w1_3, b1_3, U, V);
    k_agg<256, 256, 1, 8, 4, float><<<NNODES / 32, 512, 0, stream>>>(U, V, w2_3, b2_3, rowptr, csr_src, csr_dst, x3);

    // global max pool + FC
    k_pool<<<dim3(NGRAPHS, 8), 256, 0, stream>>>(x3, batch, poolEnc);
    k_fc<<<NGRAPHS, 128, 0, stream>>>(poolEnc, wfc, bfc, out);
}